// Round 7
// baseline (744.854 us; speedup 1.0000x reference)
//
#include <hip/hip_runtime.h>
#include <stdint.h>

#define D 512

typedef _Float16 f16;
typedef f16 f16x8 __attribute__((ext_vector_type(8)));
typedef f16 h2 __attribute__((ext_vector_type(2)));
typedef float f32x4 __attribute__((ext_vector_type(4)));
typedef unsigned int u32;
typedef u32 u32x4 __attribute__((ext_vector_type(4)));

static __device__ __forceinline__ u32 bcu(h2 h) { return __builtin_bit_cast(u32, h); }
static __device__ __forceinline__ h2 pkrtz(float a, float b) {
  return __builtin_bit_cast(h2, __builtin_amdgcn_cvt_pkrtz(a, b));
}
static __device__ __forceinline__ f16x8 frag4(u32 w0, u32 w1, u32 w2, u32 w3) {
  u32x4 u = {w0, w1, w2, w3};
  return __builtin_bit_cast(f16x8, u);
}
static __device__ __forceinline__ float fastrcp(float x) {
#if __has_builtin(__builtin_amdgcn_rcpf)
  return __builtin_amdgcn_rcpf(x);
#else
  return 1.0f / x;
#endif
}

// lhi-repack: C-layout tile pair (lane l15 = col, regs m = 4*lhi+r, plus m=16 value
// valid only on lhi==0 lanes, 0 elsewhere) -> A/B-frag (same l15, k=m=lhi*8+j, m17..31=0).
static __device__ __forceinline__ f16x8 repack_frag(float c0, float c1, float c2, float c3,
                                                    float v16, int l15, int lhi) {
  u32 t0a = bcu(pkrtz(c0, c1)), t0b = bcu(pkrtz(c2, c3));
  u32 t1a = bcu(pkrtz(v16, 0.f));
  int srcA = (((lhi * 2) & 3) << 4) | l15;
  int srcB = (((lhi * 2 + 1) & 3) << 4) | l15;
  u32 a0 = (u32)__shfl((int)t0a, srcA);
  u32 a1 = (u32)__shfl((int)t0b, srcA);
  u32 a2 = (u32)__shfl((int)t1a, srcA);
  u32 b0 = (u32)__shfl((int)t0a, srcB);
  u32 b1 = (u32)__shfl((int)t0b, srcB);
  u32 b2 = (u32)__shfl((int)t1a, srcB);
  bool lo = lhi < 2;
  return frag4(lo ? a0 : a2, lo ? a1 : 0u, lo ? b0 : b2, lo ? b1 : 0u);
}

// ---------------- prep: Wcat f16 [h][k|v][d][i] + bcat + Wqh f16 [o][i] ----------------
__global__ __launch_bounds__(256) void prep_k(
    const float* __restrict__ Wq, const float* __restrict__ Wk,
    const float* __restrict__ bk, const float* __restrict__ Wv,
    const float* __restrict__ bv, f16* __restrict__ Wcat,
    float* __restrict__ bcat, f16* __restrict__ Wqh) {
  int bid = blockIdx.x, tid = threadIdx.x;
  if (bid < 1024) {
    int h = bid >> 7, kvs = (bid >> 6) & 1, d = bid & 63;
    int srow = h * 64 + d;
    const float* src = (kvs ? Wv : Wk) + (size_t)srow * D;
    f16* dst = Wcat + (size_t)bid * D;
    for (int i = tid; i < D; i += 256) dst[i] = (f16)src[i];
    if (tid == 0) bcat[bid] = (kvs ? bv : bk)[srow];
  } else {
    int o = bid - 1024;
    for (int i = tid; i < D; i += 256) Wqh[(size_t)o * D + i] = (f16)Wq[(size_t)o * D + i];
  }
}

// ---------------- qproj (MFMA): q16h[h][bs][n][64] = LN(xf) @ Wq^T + bq ----------------
__global__ __launch_bounds__(256) void qproj_k(
    const float* __restrict__ xf, const float* __restrict__ tn_g,
    const float* __restrict__ tn_b, const f16* __restrict__ Wqh,
    const float* __restrict__ bq, f16* __restrict__ q16h) {
  __shared__ __align__(16) unsigned char lds[16384];
  const int bs = blockIdx.x, n0 = blockIdx.y * 16;
  const int tid = threadIdx.x, wv = tid >> 6, lane = tid & 63;
  const int l15 = lane & 15, lhi = lane >> 4;

  for (int rr = wv; rr < 16; rr += 4) {
    int srcn = n0 + rr;
    if (srcn > 76) srcn = 76;
    const f32x4* xr = (const f32x4*)(xf + ((size_t)(bs * 77 + srcn)) * D);
    f32x4 va = xr[lane * 2], vb = xr[lane * 2 + 1];
    float s = va[0] + va[1] + va[2] + va[3] + vb[0] + vb[1] + vb[2] + vb[3];
    float sq = va[0] * va[0] + va[1] * va[1] + va[2] * va[2] + va[3] * va[3] +
               vb[0] * vb[0] + vb[1] * vb[1] + vb[2] * vb[2] + vb[3] * vb[3];
#pragma unroll
    for (int off = 32; off; off >>= 1) {
      s += __shfl_xor(s, off);
      sq += __shfl_xor(sq, off);
    }
    float mu = s * (1.0f / 512.0f);
    float var = sq * (1.0f / 512.0f) - mu * mu;
    float rstd = rsqrtf(var + 1e-5f);
    f32x4 ga = ((const f32x4*)tn_g)[lane * 2], gb = ((const f32x4*)tn_g)[lane * 2 + 1];
    f32x4 ba = ((const f32x4*)tn_b)[lane * 2], bb = ((const f32x4*)tn_b)[lane * 2 + 1];
    uint4 u;
    u.x = bcu(pkrtz((va[0] - mu) * rstd * ga[0] + ba[0], (va[1] - mu) * rstd * ga[1] + ba[1]));
    u.y = bcu(pkrtz((va[2] - mu) * rstd * ga[2] + ba[2], (va[3] - mu) * rstd * ga[3] + ba[3]));
    u.z = bcu(pkrtz((vb[0] - mu) * rstd * gb[0] + bb[0], (vb[1] - mu) * rstd * gb[1] + bb[1]));
    u.w = bcu(pkrtz((vb[2] - mu) * rstd * gb[2] + bb[2], (vb[3] - mu) * rstd * gb[3] + bb[3]));
    *reinterpret_cast<uint4*>(lds + rr * 1024 + ((lane * 16) ^ ((rr & 7) << 4))) = u;
  }
  __syncthreads();

  f32x4 acc[8];
#pragma unroll
  for (int nt = 0; nt < 8; ++nt) {
    float bias = bq[wv * 128 + nt * 16 + l15];
    acc[nt] = (f32x4){bias, bias, bias, bias};
  }
  for (int ks = 0; ks < 16; ++ks) {
    f16x8 af = *(const f16x8*)(lds + l15 * 1024 + ((ks * 64 + lhi * 16) ^ ((l15 & 7) << 4)));
#pragma unroll
    for (int nt = 0; nt < 8; ++nt) {
      f16x8 bf = *(const f16x8*)(Wqh + (size_t)(wv * 128 + nt * 16 + l15) * D + ks * 32 + lhi * 8);
      acc[nt] = __builtin_amdgcn_mfma_f32_16x16x32_f16(af, bf, acc[nt], 0, 0, 0);
    }
  }
#pragma unroll
  for (int nt = 0; nt < 8; ++nt) {
    int col = wv * 128 + nt * 16 + l15;
    int h = col >> 6, d = col & 63;
    f16* base = q16h + ((size_t)(h * 16 + bs) * 77) * 64;
#pragma unroll
    for (int r = 0; r < 4; ++r) {
      int n = n0 + lhi * 4 + r;
      if (n < 77) base[n * 64 + d] = (f16)acc[nt][r];
    }
  }
}

// ---------------- fused: LN -> per-wave (head,batch) K,V proj -> S^T attention -> out ----
// 2 batches per block (grid 1944), 4 waves = 4 (head-half, batch) combos per head-pair.
// Wave (hh,bb): projects K and V of head hp*2+hh for rows of batch bb (16-row tile +
// broadcast row16 tile), K -> wave-private LDS (transpose), V stays in registers
// (lhi-repack), attention fully in-register. ONE barrier per block (after LN).
// LDS: xn [34][1024B swz] = 34816 + 4 x K-scratch [17][144B] = 2448 -> 44608 B.
#define KS_BASE 34816
#define LDS_TOTAL (34816 + 4 * 2448)

__global__ __launch_bounds__(256, 4) void fused_k(
    const float* __restrict__ x, const float* __restrict__ n_g,
    const float* __restrict__ n_b, const f16* __restrict__ Wcat,
    const float* __restrict__ bcat, const f16* __restrict__ q16h,
    float* __restrict__ out) {
  __shared__ __align__(16) unsigned char lds[LDS_TOTAL];
  const int b0 = blockIdx.x * 2;
  const int tid = threadIdx.x, wv = tid >> 6, lane = tid & 63;
  const int l15 = lane & 15, lhi = lane >> 4;

  // Phase 1: LayerNorm -> xn f16 rows 0..33 (swizzled)
  for (int rr = wv; rr < 34; rr += 4) {
    const f32x4* xr = (const f32x4*)(x + ((size_t)(b0 * 17 + rr)) * D);
    f32x4 va = xr[lane * 2], vb = xr[lane * 2 + 1];
    float s = va[0] + va[1] + va[2] + va[3] + vb[0] + vb[1] + vb[2] + vb[3];
    float sq = va[0] * va[0] + va[1] * va[1] + va[2] * va[2] + va[3] * va[3] +
               vb[0] * vb[0] + vb[1] * vb[1] + vb[2] * vb[2] + vb[3] * vb[3];
#pragma unroll
    for (int off = 32; off; off >>= 1) {
      s += __shfl_xor(s, off);
      sq += __shfl_xor(sq, off);
    }
    float mu = s * (1.0f / 512.0f);
    float var = sq * (1.0f / 512.0f) - mu * mu;
    float rstd = rsqrtf(var + 1e-5f);
    f32x4 ga = ((const f32x4*)n_g)[lane * 2], gb = ((const f32x4*)n_g)[lane * 2 + 1];
    f32x4 ba = ((const f32x4*)n_b)[lane * 2], bb = ((const f32x4*)n_b)[lane * 2 + 1];
    uint4 u;
    u.x = bcu(pkrtz((va[0] - mu) * rstd * ga[0] + ba[0], (va[1] - mu) * rstd * ga[1] + ba[1]));
    u.y = bcu(pkrtz((va[2] - mu) * rstd * ga[2] + ba[2], (va[3] - mu) * rstd * ga[3] + ba[3]));
    u.z = bcu(pkrtz((vb[0] - mu) * rstd * gb[0] + bb[0], (vb[1] - mu) * rstd * gb[1] + bb[1]));
    u.w = bcu(pkrtz((vb[2] - mu) * rstd * gb[2] + bb[2], (vb[3] - mu) * rstd * gb[3] + bb[3]));
    *reinterpret_cast<uint4*>(lds + rr * 1024 + ((lane * 16) ^ ((rr & 7) << 4))) = u;
  }
  __syncthreads();

  const int hh = wv >> 1, bb = wv & 1;
  const int b = b0 + bb, bs = b & 15;
  const int r0 = bb * 17;        // this wave's batch rows in xn
  const int rowA = r0 + l15;     // A-tile0 row
  const int rowB = r0 + 16;      // broadcast row
  unsigned char* ksb = lds + KS_BASE + wv * 2448;
  const float C2 = 0.18033688011112042f;  // log2(e)/8

  for (int hp = 0; hp < 4; ++hp) {
    const int head = hp * 2 + hh;
    const f16* qb = q16h + ((size_t)(head * 16 + bs) * 77) * 64;
    float* ob = out + (size_t)b * 77 * 512 + head * 64;

    f16x8 vfrag[4], kf0[2], kf1[2];

    // ---- two projection passes: kv=0 -> K (into ksb), kv=1 -> V (into vfrag) ----
#pragma unroll
    for (int kv = 0; kv < 2; ++kv) {
      const f16* wb = Wcat + (size_t)(head * 128 + kv * 64) * D;
      f32x4 acc0[4], acc1[4];
#pragma unroll
      for (int nt = 0; nt < 4; ++nt) {
        float bias = bcat[head * 128 + kv * 64 + nt * 16 + l15];
        acc0[nt] = (f32x4){bias, bias, bias, bias};
        acc1[nt] = acc0[nt];
      }
      // prefetch frags for ks=0
      f16x8 af0n = *(const f16x8*)(lds + rowA * 1024 + ((lhi * 16) ^ ((rowA & 7) << 4)));
      f16x8 af1n = *(const f16x8*)(lds + rowB * 1024 + ((lhi * 16) ^ ((rowB & 7) << 4)));
      f16x8 bfn[4];
#pragma unroll
      for (int nt = 0; nt < 4; ++nt)
        bfn[nt] = *(const f16x8*)(wb + (size_t)(nt * 16 + l15) * D + lhi * 8);
      for (int ks = 0; ks < 16; ++ks) {
        f16x8 af0 = af0n, af1 = af1n, bf[4];
#pragma unroll
        for (int nt = 0; nt < 4; ++nt) bf[nt] = bfn[nt];
        if (ks < 15) {
          int kc = (ks + 1) * 64;
          af0n = *(const f16x8*)(lds + rowA * 1024 + ((kc + lhi * 16) ^ ((rowA & 7) << 4)));
          af1n = *(const f16x8*)(lds + rowB * 1024 + ((kc + lhi * 16) ^ ((rowB & 7) << 4)));
#pragma unroll
          for (int nt = 0; nt < 4; ++nt)
            bfn[nt] = *(const f16x8*)(wb + (size_t)(nt * 16 + l15) * D + (ks + 1) * 32 + lhi * 8);
        }
#pragma unroll
        for (int nt = 0; nt < 4; ++nt) {
          acc0[nt] = __builtin_amdgcn_mfma_f32_16x16x32_f16(af0, bf[nt], acc0[nt], 0, 0, 0);
          acc1[nt] = __builtin_amdgcn_mfma_f32_16x16x32_f16(af1, bf[nt], acc1[nt], 0, 0, 0);
        }
      }
      if (kv == 0) {
        // K -> wave-private scratch [m][d] (stride 144B); transpose via LDS
#pragma unroll
        for (int nt = 0; nt < 4; ++nt) {
#pragma unroll
          for (int r = 0; r < 4; ++r)
            *(f16*)(ksb + (lhi * 4 + r) * 144 + (nt * 16 + l15) * 2) = (f16)acc0[nt][r];
          if (lhi == 0) *(f16*)(ksb + 16 * 144 + (nt * 16 + l15) * 2) = (f16)acc1[nt][0];
        }
      } else {
        // V -> B-frags in-register (lane l15 = d, k = m via lhi-repack)
#pragma unroll
        for (int nt = 0; nt < 4; ++nt) {
          float v16 = (lhi == 0) ? acc1[nt][0] : 0.f;
          vfrag[nt] = repack_frag(acc0[nt][0], acc0[nt][1], acc0[nt][2], acc0[nt][3],
                                  v16, l15, lhi);
        }
      }
    }

    // K A-frags (A rows = m; row16 broadcast) — same-wave LDS read-after-write
#pragma unroll
    for (int c = 0; c < 2; ++c) {
      kf0[c] = *(const f16x8*)(ksb + l15 * 144 + c * 64 + lhi * 16);
      kf1[c] = *(const f16x8*)(ksb + 16 * 144 + c * 64 + lhi * 16);
    }

    // ---- attention: S^T = K.Q^T, in-register softmax over m, PV from vfrag ----
#pragma unroll
    for (int nt = 0; nt < 5; ++nt) {
      int nq = nt * 16 + l15;
      if (nq > 76) nq = 76;
      f16x8 qf0 = *(const f16x8*)(qb + nq * 64 + lhi * 8);
      f16x8 qf1 = *(const f16x8*)(qb + nq * 64 + 32 + lhi * 8);
      f32x4 z = {0.f, 0.f, 0.f, 0.f};
      f32x4 s0 = z, s1 = z;
      s0 = __builtin_amdgcn_mfma_f32_16x16x32_f16(kf0[0], qf0, s0, 0, 0, 0);
      s0 = __builtin_amdgcn_mfma_f32_16x16x32_f16(kf0[1], qf1, s0, 0, 0, 0);
      s1 = __builtin_amdgcn_mfma_f32_16x16x32_f16(kf1[0], qf0, s1, 0, 0, 0);
      s1 = __builtin_amdgcn_mfma_f32_16x16x32_f16(kf1[1], qf1, s1, 0, 0, 0);
      float mx = fmaxf(fmaxf(s0[0], s0[1]), fmaxf(s0[2], s0[3]));
      mx = fmaxf(mx, __shfl_xor(mx, 16));
      mx = fmaxf(mx, __shfl_xor(mx, 32));
      mx = fmaxf(mx, s1[0]);
      float e0[4];
#pragma unroll
      for (int r = 0; r < 4; ++r) e0[r] = exp2f((s0[r] - mx) * C2);
      float e1 = exp2f((s1[0] - mx) * C2);
      float sm = e0[0] + e0[1] + e0[2] + e0[3];
      sm += __shfl_xor(sm, 16);
      sm += __shfl_xor(sm, 32);
      sm += e1;
      float inv = fastrcp(sm);
#pragma unroll
      for (int r = 0; r < 4; ++r) e0[r] *= inv;
      e1 *= inv;
      f16x8 pfrag = repack_frag(e0[0], e0[1], e0[2], e0[3], (lhi == 0) ? e1 : 0.f, l15, lhi);
#pragma unroll
      for (int dt = 0; dt < 4; ++dt) {
        f32x4 o = {0.f, 0.f, 0.f, 0.f};
        o = __builtin_amdgcn_mfma_f32_16x16x32_f16(pfrag, vfrag[dt], o, 0, 0, 0);
#pragma unroll
        for (int r = 0; r < 4; ++r) {
          int n = nt * 16 + lhi * 4 + r;
          if (n < 77) ob[(size_t)n * 512 + dt * 16 + l15] = o[r];
        }
      }
    }
  }
}

extern "C" void kernel_launch(void* const* d_in, const int* in_sizes, int n_in,
                              void* d_out, int out_size, void* d_ws, size_t ws_size,
                              hipStream_t stream) {
  const float* xf = (const float*)d_in[0];
  const float* x = (const float*)d_in[1];
  const float* tn_g = (const float*)d_in[2];
  const float* tn_b = (const float*)d_in[3];
  const float* n_g = (const float*)d_in[4];
  const float* n_b = (const float*)d_in[5];
  const float* Wq = (const float*)d_in[6];
  const float* bq = (const float*)d_in[7];
  const float* Wk = (const float*)d_in[8];
  const float* bk = (const float*)d_in[9];
  const float* Wv = (const float*)d_in[10];
  const float* bv = (const float*)d_in[11];
  float* out = (float*)d_out;

  char* ws = (char*)d_ws;
  f16* q16h = (f16*)ws;                      // 8*16*77*64*2 = 1,261,568 B (+1024 pad)
  f16* Wcat = (f16*)(ws + 1262592);          // 1024*512*2   = 1,048,576 B
  f16* Wqh = (f16*)(ws + 2311168);           // 512*512*2    = 524,288 B
  float* bcat = (float*)(ws + 2835456);      // 1024*4       = 4,096 B

  prep_k<<<1536, 256, 0, stream>>>(Wq, Wk, bk, Wv, bv, Wcat, bcat, Wqh);
  qproj_k<<<dim3(16, 5), 256, 0, stream>>>(xf, tn_g, tn_b, Wqh, bq, q16h);
  fused_k<<<1944, 256, 0, stream>>>(x, n_g, n_b, Wcat, bcat, q16h, out);
}

// Round 8
// 428.204 us; speedup vs baseline: 1.7395x; 1.7395x over previous
//
#include <hip/hip_runtime.h>
#include <stdint.h>

#define D 512

typedef _Float16 f16;
typedef f16 f16x8 __attribute__((ext_vector_type(8)));
typedef f16 h2 __attribute__((ext_vector_type(2)));
typedef float f32x4 __attribute__((ext_vector_type(4)));
typedef unsigned int u32;
typedef u32 u32x4 __attribute__((ext_vector_type(4)));

static __device__ __forceinline__ u32 bcu(h2 h) { return __builtin_bit_cast(u32, h); }
static __device__ __forceinline__ h2 pkrtz(float a, float b) {
  return __builtin_bit_cast(h2, __builtin_amdgcn_cvt_pkrtz(a, b));
}
static __device__ __forceinline__ f16x8 frag4(u32 w0, u32 w1, u32 w2, u32 w3) {
  u32x4 u = {w0, w1, w2, w3};
  return __builtin_bit_cast(f16x8, u);
}
static __device__ __forceinline__ float fastrcp(float x) {
#if __has_builtin(__builtin_amdgcn_rcpf)
  return __builtin_amdgcn_rcpf(x);
#else
  return 1.0f / x;
#endif
}

// lhi-repack (verified R5-R7): C-layout tile pair (lane l15 = col, regs m = 4*lhi+r,
// plus m=16 value on lhi==0 lanes) -> A/B-frag (same l15, k=m, m 17..31 = 0).
static __device__ __forceinline__ f16x8 repack_frag(float c0, float c1, float c2, float c3,
                                                    float v16, int l15, int lhi) {
  u32 t0a = bcu(pkrtz(c0, c1)), t0b = bcu(pkrtz(c2, c3));
  u32 t1a = bcu(pkrtz(v16, 0.f));
  int srcA = (((lhi * 2) & 3) << 4) | l15;
  int srcB = (((lhi * 2 + 1) & 3) << 4) | l15;
  u32 a0 = (u32)__shfl((int)t0a, srcA);
  u32 a1 = (u32)__shfl((int)t0b, srcA);
  u32 a2 = (u32)__shfl((int)t1a, srcA);
  u32 b0 = (u32)__shfl((int)t0a, srcB);
  u32 b1 = (u32)__shfl((int)t0b, srcB);
  u32 b2 = (u32)__shfl((int)t1a, srcB);
  bool lo = lhi < 2;
  return frag4(lo ? a0 : a2, lo ? a1 : 0u, lo ? b0 : b2, lo ? b1 : 0u);
}

// ---------------- prep_q: blocks 0..255 = Wcat/bcat prep; 256..335 = qproj ----------------
__global__ __launch_bounds__(256) void prep_q_k(
    const float* __restrict__ xf, const float* __restrict__ tn_g,
    const float* __restrict__ tn_b, const float* __restrict__ Wq,
    const float* __restrict__ bq, const float* __restrict__ Wk,
    const float* __restrict__ bk, const float* __restrict__ Wv,
    const float* __restrict__ bv, f16* __restrict__ Wcat,
    float* __restrict__ bcat, f16* __restrict__ q16h) {
  __shared__ __align__(16) unsigned char lds[16384];
  const int bid = blockIdx.x, tid = threadIdx.x;
  const int wv = tid >> 6, lane = tid & 63;
  if (bid < 256) {
    // Wcat row = bid*4 + wv: [h][k|v][d][i] f16
    int row = bid * 4 + wv;
    int h = row >> 7, kvs = (row >> 6) & 1, d = row & 63;
    int srow = h * 64 + d;
    const float* src = (kvs ? Wv : Wk) + (size_t)srow * D;
    f32x4 a = *(const f32x4*)(src + lane * 8);
    f32x4 c = *(const f32x4*)(src + lane * 8 + 4);
    uint4 u;
    u.x = bcu(pkrtz(a[0], a[1]));
    u.y = bcu(pkrtz(a[2], a[3]));
    u.z = bcu(pkrtz(c[0], c[1]));
    u.w = bcu(pkrtz(c[2], c[3]));
    *reinterpret_cast<uint4*>(Wcat + (size_t)row * D + lane * 8) = u;
    if (lane == 0) bcat[row] = (kvs ? bv : bk)[srow];
    return;
  }
  // ---- qproj: q16h[h][bs][n][64] = LN(xf) @ Wq^T + bq ----
  const int bid2 = bid - 256;
  const int bs = bid2 & 15, n0 = (bid2 >> 4) * 16;
  const int l15 = lane & 15, lhi = lane >> 4;

  for (int rr = wv; rr < 16; rr += 4) {
    int srcn = n0 + rr;
    if (srcn > 76) srcn = 76;
    const f32x4* xr = (const f32x4*)(xf + ((size_t)(bs * 77 + srcn)) * D);
    f32x4 va = xr[lane * 2], vb = xr[lane * 2 + 1];
    float s = va[0] + va[1] + va[2] + va[3] + vb[0] + vb[1] + vb[2] + vb[3];
    float sq = va[0] * va[0] + va[1] * va[1] + va[2] * va[2] + va[3] * va[3] +
               vb[0] * vb[0] + vb[1] * vb[1] + vb[2] * vb[2] + vb[3] * vb[3];
#pragma unroll
    for (int off = 32; off; off >>= 1) {
      s += __shfl_xor(s, off);
      sq += __shfl_xor(sq, off);
    }
    float mu = s * (1.0f / 512.0f);
    float var = sq * (1.0f / 512.0f) - mu * mu;
    float rstd = rsqrtf(var + 1e-5f);
    f32x4 ga = ((const f32x4*)tn_g)[lane * 2], gb = ((const f32x4*)tn_g)[lane * 2 + 1];
    f32x4 ba = ((const f32x4*)tn_b)[lane * 2], bb = ((const f32x4*)tn_b)[lane * 2 + 1];
    uint4 u;
    u.x = bcu(pkrtz((va[0] - mu) * rstd * ga[0] + ba[0], (va[1] - mu) * rstd * ga[1] + ba[1]));
    u.y = bcu(pkrtz((va[2] - mu) * rstd * ga[2] + ba[2], (va[3] - mu) * rstd * ga[3] + ba[3]));
    u.z = bcu(pkrtz((vb[0] - mu) * rstd * gb[0] + bb[0], (vb[1] - mu) * rstd * gb[1] + bb[1]));
    u.w = bcu(pkrtz((vb[2] - mu) * rstd * gb[2] + bb[2], (vb[3] - mu) * rstd * gb[3] + bb[3]));
    *reinterpret_cast<uint4*>(lds + rr * 1024 + ((lane * 16) ^ ((rr & 7) << 4))) = u;
  }
  __syncthreads();

  f32x4 acc[8];
#pragma unroll
  for (int nt = 0; nt < 8; ++nt) {
    float bias = bq[wv * 128 + nt * 16 + l15];
    acc[nt] = (f32x4){bias, bias, bias, bias};
  }
  for (int ks = 0; ks < 16; ++ks) {
    f16x8 af = *(const f16x8*)(lds + l15 * 1024 + ((ks * 64 + lhi * 16) ^ ((l15 & 7) << 4)));
#pragma unroll
    for (int nt = 0; nt < 8; ++nt) {
      const float* wr = Wq + (size_t)(wv * 128 + nt * 16 + l15) * D + ks * 32 + lhi * 8;
      f32x4 wa = *(const f32x4*)wr, wb = *(const f32x4*)(wr + 4);
      f16x8 bf = frag4(bcu(pkrtz(wa[0], wa[1])), bcu(pkrtz(wa[2], wa[3])),
                       bcu(pkrtz(wb[0], wb[1])), bcu(pkrtz(wb[2], wb[3])));
      acc[nt] = __builtin_amdgcn_mfma_f32_16x16x32_f16(af, bf, acc[nt], 0, 0, 0);
    }
  }
#pragma unroll
  for (int nt = 0; nt < 8; ++nt) {
    int col = wv * 128 + nt * 16 + l15;
    int h = col >> 6, d = col & 63;
    f16* base = q16h + ((size_t)(h * 16 + bs) * 77) * 64;
#pragma unroll
    for (int r = 0; r < 4; ++r) {
      int n = n0 + lhi * 4 + r;
      if (n < 77) base[n * 64 + d] = (f16)acc[nt][r];
    }
  }
}

// ---------------- fused: LN -> cooperative K,V proj (dbuf) -> in-reg attention -> out ----
// 2 batches/block (grid 1944), 4 waves. Per hp (head-pair): wave wv projects slab cols
// [wv*64,(wv+1)*64) over all 34 rows (3 m-tiles), stores K->KS / V->VT (double-buffered
// by hp&1), ONE barrier, then wave wv runs attention for combo wv = (hh= wv>>1, bb= wv&1).
// LDS: xn [34][1024B swz] 34816 | KS 2 bufs x 4 x [17][144B] 19584 | VT 2 x 4 x [64][48B] 24576+pad.
// Barriers: 1 (post-LN) + 4 (one per hp) = 5.
#define XN_OFF 0
#define KS_OFF 34816
#define VT_OFF 54400
#define LDS_TOTAL 79040

__global__ __launch_bounds__(256, 2) void fused_k(
    const float* __restrict__ x, const float* __restrict__ n_g,
    const float* __restrict__ n_b, const f16* __restrict__ Wcat,
    const float* __restrict__ bcat, const f16* __restrict__ q16h,
    float* __restrict__ out) {
  __shared__ __align__(16) unsigned char lds[LDS_TOTAL];
  const int b0 = blockIdx.x * 2;
  const int tid = threadIdx.x, wv = tid >> 6, lane = tid & 63;
  const int l15 = lane & 15, lhi = lane >> 4;

  // zero VT (both buffers + pad): m in [17,24) must be 0 forever (PV reads them)
  {
    uint4 z;
    z.x = z.y = z.z = z.w = 0u;
    for (int i = tid; i < 1540; i += 256)
      *reinterpret_cast<uint4*>(lds + VT_OFF + i * 16) = z;
  }

  // Phase 1: LayerNorm -> xn f16 rows 0..33 (swizzled)
  for (int rr = wv; rr < 34; rr += 4) {
    const f32x4* xr = (const f32x4*)(x + ((size_t)(b0 * 17 + rr)) * D);
    f32x4 va = xr[lane * 2], vb = xr[lane * 2 + 1];
    float s = va[0] + va[1] + va[2] + va[3] + vb[0] + vb[1] + vb[2] + vb[3];
    float sq = va[0] * va[0] + va[1] * va[1] + va[2] * va[2] + va[3] * va[3] +
               vb[0] * vb[0] + vb[1] * vb[1] + vb[2] * vb[2] + vb[3] * vb[3];
#pragma unroll
    for (int off = 32; off; off >>= 1) {
      s += __shfl_xor(s, off);
      sq += __shfl_xor(sq, off);
    }
    float mu = s * (1.0f / 512.0f);
    float var = sq * (1.0f / 512.0f) - mu * mu;
    float rstd = rsqrtf(var + 1e-5f);
    f32x4 ga = ((const f32x4*)n_g)[lane * 2], gb = ((const f32x4*)n_g)[lane * 2 + 1];
    f32x4 ba = ((const f32x4*)n_b)[lane * 2], bb = ((const f32x4*)n_b)[lane * 2 + 1];
    uint4 u;
    u.x = bcu(pkrtz((va[0] - mu) * rstd * ga[0] + ba[0], (va[1] - mu) * rstd * ga[1] + ba[1]));
    u.y = bcu(pkrtz((va[2] - mu) * rstd * ga[2] + ba[2], (va[3] - mu) * rstd * ga[3] + ba[3]));
    u.z = bcu(pkrtz((vb[0] - mu) * rstd * gb[0] + bb[0], (vb[1] - mu) * rstd * gb[1] + bb[1]));
    u.w = bcu(pkrtz((vb[2] - mu) * rstd * gb[2] + bb[2], (vb[3] - mu) * rstd * gb[3] + bb[3]));
    *reinterpret_cast<uint4*>(lds + XN_OFF + rr * 1024 + ((lane * 16) ^ ((rr & 7) << 4))) = u;
  }
  __syncthreads();

  const int hhw = wv >> 1, isv = wv & 1;  // projection role (cols)
  const int bb = wv & 1;                  // attention combo = wv
  const int b = b0 + bb, bs = b & 15;
  const float C2 = 0.18033688011112042f;  // log2(e)/8

  for (int hp = 0; hp < 4; ++hp) {
    const int buf = hp & 1;
    const int head_a = hp * 2 + (wv >> 1);

    // ---- hoist Q fragments (overlaps projection) ----
    const f16* qb = q16h + ((size_t)(head_a * 16 + bs) * 77) * 64;
    f16x8 qf[5][2];
#pragma unroll
    for (int nt = 0; nt < 5; ++nt) {
      int nq = nt * 16 + l15;
      if (nq > 76) nq = 76;
      qf[nt][0] = *(const f16x8*)(qb + nq * 64 + lhi * 8);
      qf[nt][1] = *(const f16x8*)(qb + nq * 64 + 32 + lhi * 8);
    }

    // ---- cooperative projection: slab cols [hp*256 + wv*64, +64), rows 0..33 ----
    f32x4 acc[3][4];
#pragma unroll
    for (int nt = 0; nt < 4; ++nt) {
      float bias = bcat[hp * 256 + wv * 64 + nt * 16 + l15];
      f32x4 bi = {bias, bias, bias, bias};
#pragma unroll
      for (int mt = 0; mt < 3; ++mt) acc[mt][nt] = bi;
    }
    const f16* wbase = Wcat + (size_t)(hp * 256 + wv * 64 + l15) * D;
    f16x8 bfn[4];
#pragma unroll
    for (int nt = 0; nt < 4; ++nt)
      bfn[nt] = *(const f16x8*)(wbase + (size_t)nt * 16 * D + lhi * 8);
    for (int ks = 0; ks < 16; ++ks) {
      f16x8 bf[4];
#pragma unroll
      for (int nt = 0; nt < 4; ++nt) bf[nt] = bfn[nt];
      if (ks < 15) {
#pragma unroll
        for (int nt = 0; nt < 4; ++nt)
          bfn[nt] = *(const f16x8*)(wbase + (size_t)nt * 16 * D + (ks + 1) * 32 + lhi * 8);
      }
#pragma unroll
      for (int mt = 0; mt < 3; ++mt) {
        int arow = mt * 16 + l15;
        f16x8 af = *(const f16x8*)(lds + XN_OFF + arow * 1024 +
                                   ((ks * 64 + lhi * 16) ^ ((arow & 7) << 4)));
#pragma unroll
        for (int nt = 0; nt < 4; ++nt)
          acc[mt][nt] =
              __builtin_amdgcn_mfma_f32_16x16x32_f16(af, bf[nt], acc[mt][nt], 0, 0, 0);
      }
    }
    // ---- store K/V tiles into double-buffered LDS ----
#pragma unroll
    for (int mt = 0; mt < 3; ++mt) {
#pragma unroll
      for (int nt = 0; nt < 4; ++nt) {
        int d = nt * 16 + l15;
#pragma unroll
        for (int r = 0; r < 4; ++r) {
          int mrow = mt * 16 + lhi * 4 + r;
          if (mrow < 34) {
            int bbw = mrow >= 17 ? 1 : 0;
            int m = mrow - 17 * bbw;
            int combo = hhw * 2 + bbw;
            f16 val = (f16)acc[mt][nt][r];
            if (isv)
              *(f16*)(lds + VT_OFF + buf * 12288 + combo * 3072 + d * 48 + m * 2) = val;
            else
              *(f16*)(lds + KS_OFF + buf * 9792 + combo * 2448 + m * 144 + d * 2) = val;
          }
        }
      }
    }
    __syncthreads();

    // ---- attention: combo = wv ----
    const unsigned char* ksb = lds + KS_OFF + buf * 9792 + wv * 2448;
    const unsigned char* vtb = lds + VT_OFF + buf * 12288 + wv * 3072;
    f16x8 kf0[2], kf1[2], vf[4];
#pragma unroll
    for (int c = 0; c < 2; ++c) {
      kf0[c] = *(const f16x8*)(ksb + l15 * 144 + c * 64 + lhi * 16);
      kf1[c] = *(const f16x8*)(ksb + 16 * 144 + c * 64 + lhi * 16);
    }
#pragma unroll
    for (int dt = 0; dt < 4; ++dt)
      vf[dt] = *(const f16x8*)(vtb + (dt * 16 + l15) * 48 + lhi * 16);

    float* ob = out + (size_t)b * 77 * 512 + head_a * 64;
#pragma unroll
    for (int nt = 0; nt < 5; ++nt) {
      f32x4 z = {0.f, 0.f, 0.f, 0.f};
      f32x4 s0 = z, s1 = z;
      s0 = __builtin_amdgcn_mfma_f32_16x16x32_f16(kf0[0], qf[nt][0], s0, 0, 0, 0);
      s0 = __builtin_amdgcn_mfma_f32_16x16x32_f16(kf0[1], qf[nt][1], s0, 0, 0, 0);
      s1 = __builtin_amdgcn_mfma_f32_16x16x32_f16(kf1[0], qf[nt][0], s1, 0, 0, 0);
      s1 = __builtin_amdgcn_mfma_f32_16x16x32_f16(kf1[1], qf[nt][1], s1, 0, 0, 0);
      float mx = fmaxf(fmaxf(s0[0], s0[1]), fmaxf(s0[2], s0[3]));
      mx = fmaxf(mx, __shfl_xor(mx, 16));
      mx = fmaxf(mx, __shfl_xor(mx, 32));
      mx = fmaxf(mx, s1[0]);
      float e0[4];
#pragma unroll
      for (int r = 0; r < 4; ++r) e0[r] = exp2f((s0[r] - mx) * C2);
      float e1 = exp2f((s1[0] - mx) * C2);
      float sm = e0[0] + e0[1] + e0[2] + e0[3];
      sm += __shfl_xor(sm, 16);
      sm += __shfl_xor(sm, 32);
      sm += e1;
      float inv = fastrcp(sm);
#pragma unroll
      for (int r = 0; r < 4; ++r) e0[r] *= inv;
      e1 *= inv;
      f16x8 pfrag = repack_frag(e0[0], e0[1], e0[2], e0[3], (lhi == 0) ? e1 : 0.f, l15, lhi);
#pragma unroll
      for (int dt = 0; dt < 4; ++dt) {
        f32x4 o = {0.f, 0.f, 0.f, 0.f};
        o = __builtin_amdgcn_mfma_f32_16x16x32_f16(pfrag, vf[dt], o, 0, 0, 0);
#pragma unroll
        for (int r = 0; r < 4; ++r) {
          int n = nt * 16 + lhi * 4 + r;
          if (n < 77) ob[(size_t)n * 512 + dt * 16 + l15] = o[r];
        }
      }
    }
  }
}

extern "C" void kernel_launch(void* const* d_in, const int* in_sizes, int n_in,
                              void* d_out, int out_size, void* d_ws, size_t ws_size,
                              hipStream_t stream) {
  const float* xf = (const float*)d_in[0];
  const float* x = (const float*)d_in[1];
  const float* tn_g = (const float*)d_in[2];
  const float* tn_b = (const float*)d_in[3];
  const float* n_g = (const float*)d_in[4];
  const float* n_b = (const float*)d_in[5];
  const float* Wq = (const float*)d_in[6];
  const float* bq = (const float*)d_in[7];
  const float* Wk = (const float*)d_in[8];
  const float* bk = (const float*)d_in[9];
  const float* Wv = (const float*)d_in[10];
  const float* bv = (const float*)d_in[11];
  float* out = (float*)d_out;

  char* ws = (char*)d_ws;
  f16* q16h = (f16*)ws;                      // 8*16*77*64*2 = 1,261,568 B (+1024 pad)
  f16* Wcat = (f16*)(ws + 1262592);          // 1024*512*2   = 1,048,576 B
  float* bcat = (float*)(ws + 2311168);      // 1024*4       = 4,096 B

  prep_q_k<<<336, 256, 0, stream>>>(xf, tn_g, tn_b, Wq, bq, Wk, bk, Wv, bv,
                                    Wcat, bcat, q16h);
  fused_k<<<1944, 256, 0, stream>>>(x, n_g, n_b, Wcat, bcat, q16h, out);
}